// Round 3
// baseline (691.333 us; speedup 1.0000x reference)
//
#include <hip/hip_runtime.h>
#include <hip/hip_fp16.h>
#include <stdint.h>
#include <math.h>

// MoE MLP block: router top-2 + 8 experts SiLU-GLU, fp16 MFMA.
// v3: BM=256 8-wave blocks (1/CU). GEMM1 splits gate/up across waves (same A
// amortized, acc fits); GEMM2 BM=256xBN=192 (255 blocks = 1 generation).
// gload_lds A dbuf + reg-prefetch B kept from v2; XCD-chunked grid kept.

typedef _Float16 f16;
typedef _Float16 f16x8 __attribute__((ext_vector_type(8)));
typedef float f32x4 __attribute__((ext_vector_type(4)));

#define T_TOK 2048
#define DDIM 2880
#define NEXP 8
#define IDIM 2880

#define BM 256
#define BK 64
#define NKT 45    // 2880/64
#define BN1 96
#define NNT1 30   // 2880/96
#define BN2 192
#define NNT2 15   // 2880/192
#define MAXMT 24  // 4096/256 + 8
#define NB1 (NNT1*MAXMT)  // 720 (div by 8)
#define NB2 (NNT2*MAXMT)  // 360 (div by 8)
#define SLOT_CAP 6144     // >= 4096 + 8*255

// ---- workspace layout (bytes). ybuf aliases xh (xh dead before gemm2). ----
#define HBUF_OFF 0
#define HBUF_BYTES ((size_t)SLOT_CAP*IDIM*2)          // 35.4MB
#define XH_OFF   (HBUF_OFF + HBUF_BYTES)
#define XH_BYTES ((size_t)T_TOK*DDIM*2)               // 11.8MB
#define YBUF_OFF XH_OFF                                // overlaps xh (dead)
#define YBUF_BYTES ((size_t)SLOT_CAP*DDIM*2)          // 35.4MB
#define META_OFF (YBUF_OFF + YBUF_BYTES)
// meta int32 indices
#define M_COUNT 0
#define M_CUR 8
#define M_OFFS 16      // 9 entries
#define M_NTILES 25
#define M_TILE_E 32    // 64
#define M_TILE_R0 96   // 64
#define M_SLOT_TOK 160            // SLOT_CAP
#define M_SLOT_OF (160+SLOT_CAP)  // 2*T_TOK
#define M_TOK_E (M_SLOT_OF + 2*T_TOK)
#define META_INTS (M_TOK_E + 2*T_TOK)
#define SLOTW_OFF (META_OFF + META_INTS*4)
#define TOKW_OFF  (SLOTW_OFF + SLOT_CAP*4)
#define WS_NEEDED ((size_t)TOKW_OFF + (size_t)T_TOK*2*4)

__device__ __forceinline__ int swz(int row) { return ((row ^ (row >> 3)) & 7) << 4; }

__device__ __forceinline__ void gload_lds16(const void* gp, void* lp) {
  __builtin_amdgcn_global_load_lds(
      (const __attribute__((address_space(1))) uint32_t*)gp,
      (__attribute__((address_space(3))) uint32_t*)lp,
      16, 0, 0);
}

// ---------------- router: f64 logits, top-2, pairwise softmax ----------------
__global__ __launch_bounds__(256) void k_router(
    const float* __restrict__ x, const float* __restrict__ wr,
    int* __restrict__ meta, float* __restrict__ tok_w) {
  const int lane = threadIdx.x & 63;
  const int t = blockIdx.x * 4 + (threadIdx.x >> 6);
  double acc[NEXP];
#pragma unroll
  for (int e = 0; e < NEXP; e++) acc[e] = 0.0;
  for (int d = lane; d < DDIM; d += 64) {
    float xv = x[(size_t)t * DDIM + d];
    float4 w0 = *(const float4*)(wr + (size_t)d * NEXP);
    float4 w1 = *(const float4*)(wr + (size_t)d * NEXP + 4);
    acc[0] += (double)xv * (double)w0.x;
    acc[1] += (double)xv * (double)w0.y;
    acc[2] += (double)xv * (double)w0.z;
    acc[3] += (double)xv * (double)w0.w;
    acc[4] += (double)xv * (double)w1.x;
    acc[5] += (double)xv * (double)w1.y;
    acc[6] += (double)xv * (double)w1.z;
    acc[7] += (double)xv * (double)w1.w;
  }
#pragma unroll
  for (int m = 32; m >= 1; m >>= 1) {
#pragma unroll
    for (int e = 0; e < NEXP; e++) acc[e] += __shfl_xor(acc[e], m, 64);
  }
  if (lane == 0) {
    int e0 = 0;
#pragma unroll
    for (int e = 1; e < NEXP; e++) if (acc[e] > acc[e0]) e0 = e;
    int e1 = (e0 == 0) ? 1 : 0;
#pragma unroll
    for (int e = 0; e < NEXP; e++) if (e != e0 && acc[e] > acc[e1]) e1 = e;
    double w0 = 1.0 / (1.0 + exp(acc[e1] - acc[e0]));
    meta[M_TOK_E + 2*t]     = e0;
    meta[M_TOK_E + 2*t + 1] = e1;
    tok_w[2*t]     = (float)w0;
    tok_w[2*t + 1] = (float)(1.0 - w0);
    atomicAdd(&meta[M_COUNT + e0], 1);
    atomicAdd(&meta[M_COUNT + e1], 1);
  }
}

// ---------------- x f32 -> f16 ----------------
__global__ __launch_bounds__(256) void k_xcvt(const float* __restrict__ x, f16* __restrict__ xh) {
  size_t i = ((size_t)blockIdx.x * 256 + threadIdx.x) * 8;
  float4 a = *(const float4*)(x + i);
  float4 b = *(const float4*)(x + i + 4);
  f16x8 v;
  v[0]=(f16)a.x; v[1]=(f16)a.y; v[2]=(f16)a.z; v[3]=(f16)a.w;
  v[4]=(f16)b.x; v[5]=(f16)b.y; v[6]=(f16)b.z; v[7]=(f16)b.w;
  *(f16x8*)(xh + i) = v;
}

// ---------------- scan: offsets, tile map, pad fill, zero cursors ----------------
__global__ __launch_bounds__(64) void k_scan(int* __restrict__ meta, float* __restrict__ slot_w) {
  __shared__ int s_off[NEXP], s_cnt[NEXP], s_pc[NEXP];
  if (threadIdx.x == 0) {
    int run = 0, nt = 0;
    for (int e = 0; e < NEXP; e++) {
      int c = meta[M_COUNT + e];
      int mt = (c + BM - 1) / BM;
      meta[M_OFFS + e] = run;
      s_off[e] = run; s_cnt[e] = c; s_pc[e] = mt * BM;
      for (int j = 0; j < mt; j++) { meta[M_TILE_E + nt] = e; meta[M_TILE_R0 + nt] = run + j * BM; nt++; }
      run += mt * BM;
      meta[M_CUR + e] = 0;
    }
    meta[M_OFFS + NEXP] = run;
    meta[M_NTILES] = nt;
  }
  __syncthreads();
  for (int e = 0; e < NEXP; e++) {
    for (int i = s_cnt[e] + (int)threadIdx.x; i < s_pc[e]; i += 64) {
      meta[M_SLOT_TOK + s_off[e] + i] = 0;
      slot_w[s_off[e] + i] = 0.0f;
    }
  }
}

// ---------------- scatter tokens into expert slot lists ----------------
__global__ __launch_bounds__(256) void k_scatter(int* __restrict__ meta,
    float* __restrict__ slot_w, const float* __restrict__ tok_w) {
  int t = blockIdx.x * 256 + threadIdx.x;
  if (t >= T_TOK) return;
#pragma unroll
  for (int k = 0; k < 2; k++) {
    int e = meta[M_TOK_E + 2*t + k];
    int pos = atomicAdd(&meta[M_CUR + e], 1);
    int slot = meta[M_OFFS + e] + pos;
    meta[M_SLOT_TOK + slot] = t;
    slot_w[slot] = tok_w[2*t + k];
    meta[M_SLOT_OF + 2*t + k] = slot;
  }
}

// ---------------- GEMM1: h = silu(x@Wg)*(x@Wu); 8 waves = 4m x {gate,up} ----------------
__global__ __launch_bounds__(512, 2) void k_gemm1(
    const f16* __restrict__ xh, const float* __restrict__ wg, const float* __restrict__ wu,
    f16* __restrict__ hbuf, const int* __restrict__ meta) {
  const int id = blockIdx.x;
  const int sid = (id & 7) * (NB1 / 8) + (id >> 3);
  const int mt = sid % MAXMT;
  const int nb = sid / MAXMT;
  if (mt >= meta[M_NTILES]) return;
  const int e  = meta[M_TILE_E + mt];
  const int r0 = meta[M_TILE_R0 + mt];
  const int n0 = nb * BN1;

  __shared__ ushort sA[2][BM * BK];    // 64KB, double-buffered DMA target
  __shared__ ushort sB[2][BN1 * BK];   // gate/up, 24KB

  const int tid  = threadIdx.x;
  const int lane = tid & 63;
  const int w    = tid >> 6;
  const int wm   = w >> 1;   // 0..3: row quarter
  const int gu   = w & 1;    // 0=gate wave, 1=up wave

  // A staging: 32 segs x 1KB (8 rows each); LDS linear, global pre-swizzled
  const char* a_gbase[4];
  int a_loff[4];
#pragma unroll
  for (int i = 0; i < 4; i++) {
    int seg = w * 4 + i;
    int row = seg * 8 + (lane >> 3);
    int colb = ((lane & 7) * 16) ^ swz(row);
    int tok = meta[M_SLOT_TOK + r0 + row];
    a_gbase[i] = (const char*)(xh + (size_t)tok * DDIM) + colb;
    a_loff[i] = seg * 1024;
  }

  // B staging: threads 0..191 gate, 192..383 up
  const int bm_ = tid / 192;
  const int tt  = tid % 192;
  const int bn0 = (tt % 24) * 4;
  const int bk0 = (tt / 24) * 8;
  const bool bact = tid < 384;
  const float* bsrc = (bm_ ? wu : wg) + ((size_t)e * DDIM + bk0) * IDIM + n0 + bn0;

  float4 vB[8];
  f32x4 acc[4][6];
#pragma unroll
  for (int i = 0; i < 4; i++)
#pragma unroll
    for (int j = 0; j < 6; j++) acc[i][j] = {0.f,0.f,0.f,0.f};

  // prologue: tile 0
#pragma unroll
  for (int i = 0; i < 4; i++) gload_lds16(a_gbase[i], (char*)sA[0] + a_loff[i]);
  if (bact) {
#pragma unroll
    for (int j = 0; j < 8; j++) vB[j] = *(const float4*)(bsrc + (size_t)j * IDIM);
  }

  for (int kt = 0; kt < NKT; kt++) {
    const int cur = kt & 1;
    __syncthreads();   // (a) drains prefetches
    if (bact) {
#pragma unroll
      for (int c = 0; c < 4; c++) {
        f16x8 p;
#pragma unroll
        for (int j = 0; j < 8; j++) {
          float fc = (c==0) ? vB[j].x : (c==1) ? vB[j].y : (c==2) ? vB[j].z : vB[j].w;
          p[j] = (f16)fc;
        }
        *(f16x8*)((char*)sB[bm_] + (bn0 + c) * 128 + ((bk0 * 2) ^ swz(bn0 + c))) = p;
      }
    }
    __syncthreads();   // (b) sB(kt) visible
    if (kt + 1 < NKT) {
#pragma unroll
      for (int i = 0; i < 4; i++)
        gload_lds16(a_gbase[i] + (kt + 1) * 128, (char*)sA[cur ^ 1] + a_loff[i]);
      if (bact) {
        const float* bs = bsrc + (size_t)(kt + 1) * BK * IDIM;
#pragma unroll
        for (int j = 0; j < 8; j++) vB[j] = *(const float4*)(bs + (size_t)j * IDIM);
      }
    }
#pragma unroll
    for (int kk = 0; kk < 2; kk++) {
      const int gb = kk * 64 + ((lane >> 4) * 16);
      f16x8 af[4], bf[6];
#pragma unroll
      for (int fm = 0; fm < 4; fm++) {
        int row = wm * 64 + fm * 16 + (lane & 15);
        af[fm] = *(const f16x8*)((const char*)sA[cur] + row * 128 + (gb ^ swz(row)));
      }
#pragma unroll
      for (int fn = 0; fn < 6; fn++) {
        int row = fn * 16 + (lane & 15);
        bf[fn] = *(const f16x8*)((const char*)sB[gu] + row * 128 + (gb ^ swz(row)));
      }
#pragma unroll
      for (int fm = 0; fm < 4; fm++)
#pragma unroll
        for (int fn = 0; fn < 6; fn++)
          acc[fm][fn] = __builtin_amdgcn_mfma_f32_16x16x32_f16(af[fm], bf[fn], acc[fm][fn], 0, 0, 0);
    }
  }

  // epilogue: up-waves pass U via LDS (f32, stride 100 words), 2 rounds of 32 rows
  float* u_lds = (float*)&sA[0][0];   // 4*32*100*4 = 51.2KB <= 64KB
  const int rl4 = (lane >> 4) * 4;
  const int cl  = lane & 15;
#pragma unroll
  for (int r = 0; r < 2; r++) {
    __syncthreads();
    if (gu == 1) {
#pragma unroll
      for (int fi = 0; fi < 2; fi++)
#pragma unroll
        for (int fn = 0; fn < 6; fn++)
#pragma unroll
          for (int j = 0; j < 4; j++)
            u_lds[wm * 3200 + (fi * 16 + rl4 + j) * 100 + fn * 16 + cl] = acc[2*r + fi][fn][j];
    }
    __syncthreads();
    if (gu == 0) {
#pragma unroll
      for (int fi = 0; fi < 2; fi++) {
        int fm = 2*r + fi;
#pragma unroll
        for (int fn = 0; fn < 6; fn++)
#pragma unroll
          for (int j = 0; j < 4; j++) {
            float u = u_lds[wm * 3200 + (fi * 16 + rl4 + j) * 100 + fn * 16 + cl];
            float g = acc[fm][fn][j];
            float h = g * u / (1.0f + __expf(-g));
            hbuf[(size_t)(r0 + wm * 64 + fm * 16 + rl4 + j) * IDIM + n0 + fn * 16 + cl] = (f16)h;
          }
      }
    }
  }
}

// ---------------- GEMM2: y = (h @ Wd) * slot_w; 8 waves = 4m x 2n ----------------
__global__ __launch_bounds__(512, 2) void k_gemm2(
    const f16* __restrict__ hbuf, const float* __restrict__ wd,
    f16* __restrict__ ybuf, const int* __restrict__ meta, const float* __restrict__ slot_w) {
  const int id = blockIdx.x;
  const int sid = (id & 7) * (NB2 / 8) + (id >> 3);
  const int mt = sid % MAXMT;
  const int nb = sid / MAXMT;
  if (mt >= meta[M_NTILES]) return;
  const int e  = meta[M_TILE_E + mt];
  const int r0 = meta[M_TILE_R0 + mt];
  const int n0 = nb * BN2;

  __shared__ ushort sA[2][BM * BK];    // 64KB
  __shared__ ushort sB1[BN2 * BK];     // 24KB

  const int tid  = threadIdx.x;
  const int lane = tid & 63;
  const int w    = tid >> 6;
  const int wm   = w >> 1;   // 0..3
  const int wn   = w & 1;    // 0..1

  const char* a_gbase[4];
  int a_loff[4];
#pragma unroll
  for (int i = 0; i < 4; i++) {
    int seg = w * 4 + i;
    int row = seg * 8 + (lane >> 3);
    int colb = ((lane & 7) * 16) ^ swz(row);
    a_gbase[i] = (const char*)(hbuf + (size_t)(r0 + row) * IDIM) + colb;
    a_loff[i] = seg * 1024;
  }

  const int half = tid / 192;          // 0,1 active n-halves
  const int tt   = tid % 192;
  const int bn0  = half * 96 + (tt % 24) * 4;
  const int bk0  = (tt / 24) * 8;
  const bool bact = tid < 384;
  const float* bsrc = wd + ((size_t)e * IDIM + bk0) * DDIM + n0 + bn0;

  float4 vB[8];
  f32x4 acc[4][6];
#pragma unroll
  for (int i = 0; i < 4; i++)
#pragma unroll
    for (int j = 0; j < 6; j++) acc[i][j] = {0.f,0.f,0.f,0.f};

#pragma unroll
  for (int i = 0; i < 4; i++) gload_lds16(a_gbase[i], (char*)sA[0] + a_loff[i]);
  if (bact) {
#pragma unroll
    for (int j = 0; j < 8; j++) vB[j] = *(const float4*)(bsrc + (size_t)j * DDIM);
  }

  for (int kt = 0; kt < NKT; kt++) {
    const int cur = kt & 1;
    __syncthreads();   // (a)
    if (bact) {
#pragma unroll
      for (int c = 0; c < 4; c++) {
        f16x8 p;
#pragma unroll
        for (int j = 0; j < 8; j++) {
          float fc = (c==0) ? vB[j].x : (c==1) ? vB[j].y : (c==2) ? vB[j].z : vB[j].w;
          p[j] = (f16)fc;
        }
        *(f16x8*)((char*)sB1 + (bn0 + c) * 128 + ((bk0 * 2) ^ swz(bn0 + c))) = p;
      }
    }
    __syncthreads();   // (b)
    if (kt + 1 < NKT) {
#pragma unroll
      for (int i = 0; i < 4; i++)
        gload_lds16(a_gbase[i] + (kt + 1) * 128, (char*)sA[cur ^ 1] + a_loff[i]);
      if (bact) {
        const float* bs = bsrc + (size_t)(kt + 1) * BK * DDIM;
#pragma unroll
        for (int j = 0; j < 8; j++) vB[j] = *(const float4*)(bs + (size_t)j * DDIM);
      }
    }
#pragma unroll
    for (int kk = 0; kk < 2; kk++) {
      const int gb = kk * 64 + ((lane >> 4) * 16);
      f16x8 af[4], bf[6];
#pragma unroll
      for (int fm = 0; fm < 4; fm++) {
        int row = wm * 64 + fm * 16 + (lane & 15);
        af[fm] = *(const f16x8*)((const char*)sA[cur] + row * 128 + (gb ^ swz(row)));
      }
#pragma unroll
      for (int fn = 0; fn < 6; fn++) {
        int row = wn * 96 + fn * 16 + (lane & 15);
        bf[fn] = *(const f16x8*)((const char*)sB1 + row * 128 + (gb ^ swz(row)));
      }
#pragma unroll
      for (int fm = 0; fm < 4; fm++)
#pragma unroll
        for (int fn = 0; fn < 6; fn++)
          acc[fm][fn] = __builtin_amdgcn_mfma_f32_16x16x32_f16(af[fm], bf[fn], acc[fm][fn], 0, 0, 0);
    }
  }

  const int rl4 = (lane >> 4) * 4;
  const int cl  = lane & 15;
#pragma unroll
  for (int fm = 0; fm < 4; fm++)
#pragma unroll
    for (int j = 0; j < 4; j++) {
      int row = wm * 64 + fm * 16 + rl4 + j;
      int slot = r0 + row;
      float wv = slot_w[slot];
#pragma unroll
      for (int fn = 0; fn < 6; fn++) {
        int col = n0 + wn * 96 + fn * 16 + cl;
        ybuf[(size_t)slot * DDIM + col] = (f16)(acc[fm][fn][j] * wv);
      }
    }
}

// ---------------- combine: out[t] = y[slot0] + y[slot1] ----------------
__global__ __launch_bounds__(256) void k_combine(const f16* __restrict__ ybuf,
    const int* __restrict__ meta, float* __restrict__ out) {
  size_t idx = (size_t)blockIdx.x * 256 + threadIdx.x;
  int t = (int)(idx / (DDIM/8));
  int c = (int)(idx % (DDIM/8));
  int s0 = meta[M_SLOT_OF + 2*t];
  int s1 = meta[M_SLOT_OF + 2*t + 1];
  f16x8 a = *(const f16x8*)(ybuf + (size_t)s0 * DDIM + c*8);
  f16x8 b = *(const f16x8*)(ybuf + (size_t)s1 * DDIM + c*8);
  float4 o0, o1;
  o0.x = (float)a[0] + (float)b[0];
  o0.y = (float)a[1] + (float)b[1];
  o0.z = (float)a[2] + (float)b[2];
  o0.w = (float)a[3] + (float)b[3];
  o1.x = (float)a[4] + (float)b[4];
  o1.y = (float)a[5] + (float)b[5];
  o1.z = (float)a[6] + (float)b[6];
  o1.w = (float)a[7] + (float)b[7];
  float* op = out + (size_t)t * DDIM + c*8;
  *(float4*)op = o0;
  *(float4*)(op + 4) = o1;
}

extern "C" void kernel_launch(void* const* d_in, const int* in_sizes, int n_in,
                              void* d_out, int out_size, void* d_ws, size_t ws_size,
                              hipStream_t stream) {
  const float* x  = (const float*)d_in[0];
  const float* wr = (const float*)d_in[1];
  const float* wg = (const float*)d_in[2];
  const float* wu = (const float*)d_in[3];
  const float* wd = (const float*)d_in[4];
  float* out = (float*)d_out;
  char* ws = (char*)d_ws;
  if (ws_size < WS_NEEDED) return;  // fail loudly (output stays poisoned)

  f16* hbuf  = (f16*)(ws + HBUF_OFF);
  f16* xh    = (f16*)(ws + XH_OFF);
  f16* ybuf  = (f16*)(ws + YBUF_OFF);   // aliases xh (dead by gemm2)
  int* meta  = (int*)(ws + META_OFF);
  float* slot_w = (float*)(ws + SLOTW_OFF);
  float* tok_w  = (float*)(ws + TOKW_OFF);

  hipMemsetAsync(meta + M_COUNT, 0, NEXP * sizeof(int), stream);
  k_router<<<T_TOK/4, 256, 0, stream>>>(x, wr, meta, tok_w);
  k_xcvt<<<(T_TOK*DDIM/8 + 255)/256, 256, 0, stream>>>(x, xh);
  k_scan<<<1, 64, 0, stream>>>(meta, slot_w);
  k_scatter<<<(T_TOK + 255)/256, 256, 0, stream>>>(meta, slot_w, tok_w);
  k_gemm1<<<NB1, 512, 0, stream>>>(xh, wg, wu, hbuf, meta);
  k_gemm2<<<NB2, 512, 0, stream>>>(hbuf, wd, ybuf, meta, slot_w);
  k_combine<<<(T_TOK*DDIM/8 + 255)/256, 256, 0, stream>>>(ybuf, meta, out);
}

// Round 4
// 687.297 us; speedup vs baseline: 1.0059x; 1.0059x over previous
//
#include <hip/hip_runtime.h>
#include <hip/hip_fp16.h>
#include <stdint.h>
#include <math.h>

// MoE MLP block: router top-2 + 8 experts SiLU-GLU, fp16 MFMA.
// v4: single-barrier pipelined k-loop (issue A-DMA + B-gloads for kt+1 BEFORE
// MFMA(kt); convert+ds_write B AFTER; one __syncthreads per k-step). sA and sB
// both double-buffered. BM=256, 8 waves. XCD-chunked grid kept.

typedef _Float16 f16;
typedef _Float16 f16x8 __attribute__((ext_vector_type(8)));
typedef float f32x4 __attribute__((ext_vector_type(4)));

#define T_TOK 2048
#define DDIM 2880
#define NEXP 8
#define IDIM 2880

#define BM 256
#define BK 64
#define NKT 45    // 2880/64
#define BN1 96
#define NNT1 30   // 2880/96
#define BN2 192
#define NNT2 15   // 2880/192
#define MAXMT 24  // 4096/256 + 8
#define NB1 (NNT1*MAXMT)  // 720 (div by 8)
#define NB2 (NNT2*MAXMT)  // 360 (div by 8)
#define SLOT_CAP 6144     // >= 4096 + 8*255

// ---- workspace layout (bytes). ybuf aliases xh (xh dead before gemm2). ----
#define HBUF_OFF 0
#define HBUF_BYTES ((size_t)SLOT_CAP*IDIM*2)          // 35.4MB
#define XH_OFF   (HBUF_OFF + HBUF_BYTES)
#define XH_BYTES ((size_t)T_TOK*DDIM*2)               // 11.8MB
#define YBUF_OFF XH_OFF                                // overlaps xh (dead)
#define YBUF_BYTES ((size_t)SLOT_CAP*DDIM*2)          // 35.4MB
#define META_OFF (YBUF_OFF + YBUF_BYTES)
// meta int32 indices
#define M_COUNT 0
#define M_CUR 8
#define M_OFFS 16      // 9 entries
#define M_NTILES 25
#define M_TILE_E 32    // 64
#define M_TILE_R0 96   // 64
#define M_SLOT_TOK 160            // SLOT_CAP
#define M_SLOT_OF (160+SLOT_CAP)  // 2*T_TOK
#define M_TOK_E (M_SLOT_OF + 2*T_TOK)
#define META_INTS (M_TOK_E + 2*T_TOK)
#define SLOTW_OFF (META_OFF + META_INTS*4)
#define TOKW_OFF  (SLOTW_OFF + SLOT_CAP*4)
#define WS_NEEDED ((size_t)TOKW_OFF + (size_t)T_TOK*2*4)

__device__ __forceinline__ int swz(int row) { return ((row ^ (row >> 3)) & 7) << 4; }

__device__ __forceinline__ void gload_lds16(const void* gp, void* lp) {
  __builtin_amdgcn_global_load_lds(
      (const __attribute__((address_space(1))) uint32_t*)gp,
      (__attribute__((address_space(3))) uint32_t*)lp,
      16, 0, 0);
}

// ---------------- router: f64 logits, top-2, pairwise softmax ----------------
__global__ __launch_bounds__(256) void k_router(
    const float* __restrict__ x, const float* __restrict__ wr,
    int* __restrict__ meta, float* __restrict__ tok_w) {
  const int lane = threadIdx.x & 63;
  const int t = blockIdx.x * 4 + (threadIdx.x >> 6);
  double acc[NEXP];
#pragma unroll
  for (int e = 0; e < NEXP; e++) acc[e] = 0.0;
  for (int d = lane; d < DDIM; d += 64) {
    float xv = x[(size_t)t * DDIM + d];
    float4 w0 = *(const float4*)(wr + (size_t)d * NEXP);
    float4 w1 = *(const float4*)(wr + (size_t)d * NEXP + 4);
    acc[0] += (double)xv * (double)w0.x;
    acc[1] += (double)xv * (double)w0.y;
    acc[2] += (double)xv * (double)w0.z;
    acc[3] += (double)xv * (double)w0.w;
    acc[4] += (double)xv * (double)w1.x;
    acc[5] += (double)xv * (double)w1.y;
    acc[6] += (double)xv * (double)w1.z;
    acc[7] += (double)xv * (double)w1.w;
  }
#pragma unroll
  for (int m = 32; m >= 1; m >>= 1) {
#pragma unroll
    for (int e = 0; e < NEXP; e++) acc[e] += __shfl_xor(acc[e], m, 64);
  }
  if (lane == 0) {
    int e0 = 0;
#pragma unroll
    for (int e = 1; e < NEXP; e++) if (acc[e] > acc[e0]) e0 = e;
    int e1 = (e0 == 0) ? 1 : 0;
#pragma unroll
    for (int e = 0; e < NEXP; e++) if (e != e0 && acc[e] > acc[e1]) e1 = e;
    double w0 = 1.0 / (1.0 + exp(acc[e1] - acc[e0]));
    meta[M_TOK_E + 2*t]     = e0;
    meta[M_TOK_E + 2*t + 1] = e1;
    tok_w[2*t]     = (float)w0;
    tok_w[2*t + 1] = (float)(1.0 - w0);
    atomicAdd(&meta[M_COUNT + e0], 1);
    atomicAdd(&meta[M_COUNT + e1], 1);
  }
}

// ---------------- x f32 -> f16 ----------------
__global__ __launch_bounds__(256) void k_xcvt(const float* __restrict__ x, f16* __restrict__ xh) {
  size_t i = ((size_t)blockIdx.x * 256 + threadIdx.x) * 8;
  float4 a = *(const float4*)(x + i);
  float4 b = *(const float4*)(x + i + 4);
  f16x8 v;
  v[0]=(f16)a.x; v[1]=(f16)a.y; v[2]=(f16)a.z; v[3]=(f16)a.w;
  v[4]=(f16)b.x; v[5]=(f16)b.y; v[6]=(f16)b.z; v[7]=(f16)b.w;
  *(f16x8*)(xh + i) = v;
}

// ---------------- scan: offsets, tile map, pad fill, zero cursors ----------------
__global__ __launch_bounds__(64) void k_scan(int* __restrict__ meta, float* __restrict__ slot_w) {
  __shared__ int s_off[NEXP], s_cnt[NEXP], s_pc[NEXP];
  if (threadIdx.x == 0) {
    int run = 0, nt = 0;
    for (int e = 0; e < NEXP; e++) {
      int c = meta[M_COUNT + e];
      int mt = (c + BM - 1) / BM;
      meta[M_OFFS + e] = run;
      s_off[e] = run; s_cnt[e] = c; s_pc[e] = mt * BM;
      for (int j = 0; j < mt; j++) { meta[M_TILE_E + nt] = e; meta[M_TILE_R0 + nt] = run + j * BM; nt++; }
      run += mt * BM;
      meta[M_CUR + e] = 0;
    }
    meta[M_OFFS + NEXP] = run;
    meta[M_NTILES] = nt;
  }
  __syncthreads();
  for (int e = 0; e < NEXP; e++) {
    for (int i = s_cnt[e] + (int)threadIdx.x; i < s_pc[e]; i += 64) {
      meta[M_SLOT_TOK + s_off[e] + i] = 0;
      slot_w[s_off[e] + i] = 0.0f;
    }
  }
}

// ---------------- scatter tokens into expert slot lists ----------------
__global__ __launch_bounds__(256) void k_scatter(int* __restrict__ meta,
    float* __restrict__ slot_w, const float* __restrict__ tok_w) {
  int t = blockIdx.x * 256 + threadIdx.x;
  if (t >= T_TOK) return;
#pragma unroll
  for (int k = 0; k < 2; k++) {
    int e = meta[M_TOK_E + 2*t + k];
    int pos = atomicAdd(&meta[M_CUR + e], 1);
    int slot = meta[M_OFFS + e] + pos;
    meta[M_SLOT_TOK + slot] = t;
    slot_w[slot] = tok_w[2*t + k];
    meta[M_SLOT_OF + 2*t + k] = slot;
  }
}

// ---------------- GEMM1: h = silu(x@Wg)*(x@Wu); 8 waves = 4m x {gate,up} ----------------
__global__ __launch_bounds__(512, 2) void k_gemm1(
    const f16* __restrict__ xh, const float* __restrict__ wg, const float* __restrict__ wu,
    f16* __restrict__ hbuf, const int* __restrict__ meta) {
  const int id = blockIdx.x;
  const int sid = (id & 7) * (NB1 / 8) + (id >> 3);
  const int mt = sid % MAXMT;
  const int nb = sid / MAXMT;
  if (mt >= meta[M_NTILES]) return;
  const int e  = meta[M_TILE_E + mt];
  const int r0 = meta[M_TILE_R0 + mt];
  const int n0 = nb * BN1;

  __shared__ ushort sA[2][BM * BK];       // 64KB, double-buffered DMA target
  __shared__ ushort sB[2][2][BN1 * BK];   // [buf][gate/up], 48KB

  const int tid  = threadIdx.x;
  const int lane = tid & 63;
  const int w    = tid >> 6;
  const int wm   = w >> 1;   // 0..3: row quarter
  const int gu   = w & 1;    // 0=gate wave, 1=up wave

  // A staging: 32 segs x 1KB (8 rows each); LDS linear, global pre-swizzled
  const char* a_gbase[4];
  int a_loff[4];
#pragma unroll
  for (int i = 0; i < 4; i++) {
    int seg = w * 4 + i;
    int row = seg * 8 + (lane >> 3);
    int colb = ((lane & 7) * 16) ^ swz(row);
    int tok = meta[M_SLOT_TOK + r0 + row];
    a_gbase[i] = (const char*)(xh + (size_t)tok * DDIM) + colb;
    a_loff[i] = seg * 1024;
  }

  // B staging: threads 0..191 gate, 192..383 up
  const int bm_ = tid / 192;
  const int tt  = tid % 192;
  const int bn0 = (tt % 24) * 4;
  const int bk0 = (tt / 24) * 8;
  const bool bact = tid < 384;
  const float* bsrc = (bm_ ? wu : wg) + ((size_t)e * DDIM + bk0) * IDIM + n0 + bn0;

  float4 vB[8];
  f32x4 acc[4][6];
#pragma unroll
  for (int i = 0; i < 4; i++)
#pragma unroll
    for (int j = 0; j < 6; j++) acc[i][j] = {0.f,0.f,0.f,0.f};

  // ---- prologue: tile 0 ----
#pragma unroll
  for (int i = 0; i < 4; i++) gload_lds16(a_gbase[i], (char*)sA[0] + a_loff[i]);
  if (bact) {
#pragma unroll
    for (int j = 0; j < 8; j++) vB[j] = *(const float4*)(bsrc + (size_t)j * IDIM);
#pragma unroll
    for (int c = 0; c < 4; c++) {
      f16x8 p;
#pragma unroll
      for (int j = 0; j < 8; j++) {
        float fc = (c==0) ? vB[j].x : (c==1) ? vB[j].y : (c==2) ? vB[j].z : vB[j].w;
        p[j] = (f16)fc;
      }
      *(f16x8*)((char*)sB[0][bm_] + (bn0 + c) * 128 + ((bk0 * 2) ^ swz(bn0 + c))) = p;
    }
  }
  __syncthreads();   // drains A-DMA(0), publishes sB[0]

  // ---- main loop: ONE barrier per k-step ----
  for (int kt = 0; kt < NKT; kt++) {
    const int cur = kt & 1;
    // issue next tile's loads: fly during MFMA phase
    if (kt + 1 < NKT) {
#pragma unroll
      for (int i = 0; i < 4; i++)
        gload_lds16(a_gbase[i] + (kt + 1) * 128, (char*)sA[cur ^ 1] + a_loff[i]);
      if (bact) {
        const float* bs = bsrc + (size_t)(kt + 1) * BK * IDIM;
#pragma unroll
        for (int j = 0; j < 8; j++) vB[j] = *(const float4*)(bs + (size_t)j * IDIM);
      }
    }
    // MFMA on current tile
#pragma unroll
    for (int kk = 0; kk < 2; kk++) {
      const int gb = kk * 64 + ((lane >> 4) * 16);
      f16x8 af[4], bf[6];
#pragma unroll
      for (int fm = 0; fm < 4; fm++) {
        int row = wm * 64 + fm * 16 + (lane & 15);
        af[fm] = *(const f16x8*)((const char*)sA[cur] + row * 128 + (gb ^ swz(row)));
      }
#pragma unroll
      for (int fn = 0; fn < 6; fn++) {
        int row = fn * 16 + (lane & 15);
        bf[fn] = *(const f16x8*)((const char*)sB[cur][gu] + row * 128 + (gb ^ swz(row)));
      }
#pragma unroll
      for (int fm = 0; fm < 4; fm++)
#pragma unroll
        for (int fn = 0; fn < 6; fn++)
          acc[fm][fn] = __builtin_amdgcn_mfma_f32_16x16x32_f16(af[fm], bf[fn], acc[fm][fn], 0, 0, 0);
    }
    // convert + publish next B tile (waits vB here, after MFMA)
    if (kt + 1 < NKT && bact) {
#pragma unroll
      for (int c = 0; c < 4; c++) {
        f16x8 p;
#pragma unroll
        for (int j = 0; j < 8; j++) {
          float fc = (c==0) ? vB[j].x : (c==1) ? vB[j].y : (c==2) ? vB[j].z : vB[j].w;
          p[j] = (f16)fc;
        }
        *(f16x8*)((char*)sB[cur ^ 1][bm_] + (bn0 + c) * 128 + ((bk0 * 2) ^ swz(bn0 + c))) = p;
      }
    }
    __syncthreads();   // vmcnt(0)+lgkmcnt(0) drain lands after MFMA+convert
  }

  // epilogue: up-waves pass U via LDS (f32, stride 100 words), 2 rounds of 32 rows
  float* u_lds = (float*)&sA[0][0];   // 4*32*100*4 = 51.2KB <= 64KB
  const int rl4 = (lane >> 4) * 4;
  const int cl  = lane & 15;
#pragma unroll
  for (int r = 0; r < 2; r++) {
    __syncthreads();
    if (gu == 1) {
#pragma unroll
      for (int fi = 0; fi < 2; fi++)
#pragma unroll
        for (int fn = 0; fn < 6; fn++)
#pragma unroll
          for (int j = 0; j < 4; j++)
            u_lds[wm * 3200 + (fi * 16 + rl4 + j) * 100 + fn * 16 + cl] = acc[2*r + fi][fn][j];
    }
    __syncthreads();
    if (gu == 0) {
#pragma unroll
      for (int fi = 0; fi < 2; fi++) {
        int fm = 2*r + fi;
#pragma unroll
        for (int fn = 0; fn < 6; fn++)
#pragma unroll
          for (int j = 0; j < 4; j++) {
            float u = u_lds[wm * 3200 + (fi * 16 + rl4 + j) * 100 + fn * 16 + cl];
            float g = acc[fm][fn][j];
            float h = g * u / (1.0f + __expf(-g));
            hbuf[(size_t)(r0 + wm * 64 + fm * 16 + rl4 + j) * IDIM + n0 + fn * 16 + cl] = (f16)h;
          }
      }
    }
  }
}

// ---------------- GEMM2: y = (h @ Wd) * slot_w; 8 waves = 4m x 2n ----------------
__global__ __launch_bounds__(512, 2) void k_gemm2(
    const f16* __restrict__ hbuf, const float* __restrict__ wd,
    f16* __restrict__ ybuf, const int* __restrict__ meta, const float* __restrict__ slot_w) {
  const int id = blockIdx.x;
  const int sid = (id & 7) * (NB2 / 8) + (id >> 3);
  const int mt = sid % MAXMT;
  const int nb = sid / MAXMT;
  if (mt >= meta[M_NTILES]) return;
  const int e  = meta[M_TILE_E + mt];
  const int r0 = meta[M_TILE_R0 + mt];
  const int n0 = nb * BN2;

  __shared__ ushort sA[2][BM * BK];     // 64KB
  __shared__ ushort sB1[2][BN2 * BK];   // 48KB

  const int tid  = threadIdx.x;
  const int lane = tid & 63;
  const int w    = tid >> 6;
  const int wm   = w >> 1;   // 0..3
  const int wn   = w & 1;    // 0..1

  const char* a_gbase[4];
  int a_loff[4];
#pragma unroll
  for (int i = 0; i < 4; i++) {
    int seg = w * 4 + i;
    int row = seg * 8 + (lane >> 3);
    int colb = ((lane & 7) * 16) ^ swz(row);
    a_gbase[i] = (const char*)(hbuf + (size_t)(r0 + row) * IDIM) + colb;
    a_loff[i] = seg * 1024;
  }

  const int half = tid / 192;          // 0,1 active n-halves
  const int tt   = tid % 192;
  const int bn0  = half * 96 + (tt % 24) * 4;
  const int bk0  = (tt / 24) * 8;
  const bool bact = tid < 384;
  const float* bsrc = wd + ((size_t)e * IDIM + bk0) * DDIM + n0 + bn0;

  float4 vB[8];
  f32x4 acc[4][6];
#pragma unroll
  for (int i = 0; i < 4; i++)
#pragma unroll
    for (int j = 0; j < 6; j++) acc[i][j] = {0.f,0.f,0.f,0.f};

  // ---- prologue ----
#pragma unroll
  for (int i = 0; i < 4; i++) gload_lds16(a_gbase[i], (char*)sA[0] + a_loff[i]);
  if (bact) {
#pragma unroll
    for (int j = 0; j < 8; j++) vB[j] = *(const float4*)(bsrc + (size_t)j * DDIM);
#pragma unroll
    for (int c = 0; c < 4; c++) {
      f16x8 p;
#pragma unroll
      for (int j = 0; j < 8; j++) {
        float fc = (c==0) ? vB[j].x : (c==1) ? vB[j].y : (c==2) ? vB[j].z : vB[j].w;
        p[j] = (f16)fc;
      }
      *(f16x8*)((char*)sB1[0] + (bn0 + c) * 128 + ((bk0 * 2) ^ swz(bn0 + c))) = p;
    }
  }
  __syncthreads();

  // ---- main loop: ONE barrier per k-step ----
  for (int kt = 0; kt < NKT; kt++) {
    const int cur = kt & 1;
    if (kt + 1 < NKT) {
#pragma unroll
      for (int i = 0; i < 4; i++)
        gload_lds16(a_gbase[i] + (kt + 1) * 128, (char*)sA[cur ^ 1] + a_loff[i]);
      if (bact) {
        const float* bs = bsrc + (size_t)(kt + 1) * BK * DDIM;
#pragma unroll
        for (int j = 0; j < 8; j++) vB[j] = *(const float4*)(bs + (size_t)j * DDIM);
      }
    }
#pragma unroll
    for (int kk = 0; kk < 2; kk++) {
      const int gb = kk * 64 + ((lane >> 4) * 16);
      f16x8 af[4], bf[6];
#pragma unroll
      for (int fm = 0; fm < 4; fm++) {
        int row = wm * 64 + fm * 16 + (lane & 15);
        af[fm] = *(const f16x8*)((const char*)sA[cur] + row * 128 + (gb ^ swz(row)));
      }
#pragma unroll
      for (int fn = 0; fn < 6; fn++) {
        int row = wn * 96 + fn * 16 + (lane & 15);
        bf[fn] = *(const f16x8*)((const char*)sB1[cur] + row * 128 + (gb ^ swz(row)));
      }
#pragma unroll
      for (int fm = 0; fm < 4; fm++)
#pragma unroll
        for (int fn = 0; fn < 6; fn++)
          acc[fm][fn] = __builtin_amdgcn_mfma_f32_16x16x32_f16(af[fm], bf[fn], acc[fm][fn], 0, 0, 0);
    }
    if (kt + 1 < NKT && bact) {
#pragma unroll
      for (int c = 0; c < 4; c++) {
        f16x8 p;
#pragma unroll
        for (int j = 0; j < 8; j++) {
          float fc = (c==0) ? vB[j].x : (c==1) ? vB[j].y : (c==2) ? vB[j].z : vB[j].w;
          p[j] = (f16)fc;
        }
        *(f16x8*)((char*)sB1[cur ^ 1] + (bn0 + c) * 128 + ((bk0 * 2) ^ swz(bn0 + c))) = p;
      }
    }
    __syncthreads();
  }

  const int rl4 = (lane >> 4) * 4;
  const int cl  = lane & 15;
#pragma unroll
  for (int fm = 0; fm < 4; fm++)
#pragma unroll
    for (int j = 0; j < 4; j++) {
      int row = wm * 64 + fm * 16 + rl4 + j;
      int slot = r0 + row;
      float wv = slot_w[slot];
#pragma unroll
      for (int fn = 0; fn < 6; fn++) {
        int col = n0 + wn * 96 + fn * 16 + cl;
        ybuf[(size_t)slot * DDIM + col] = (f16)(acc[fm][fn][j] * wv);
      }
    }
}

// ---------------- combine: out[t] = y[slot0] + y[slot1] ----------------
__global__ __launch_bounds__(256) void k_combine(const f16* __restrict__ ybuf,
    const int* __restrict__ meta, float* __restrict__ out) {
  size_t idx = (size_t)blockIdx.x * 256 + threadIdx.x;
  int t = (int)(idx / (DDIM/8));
  int c = (int)(idx % (DDIM/8));
  int s0 = meta[M_SLOT_OF + 2*t];
  int s1 = meta[M_SLOT_OF + 2*t + 1];
  f16x8 a = *(const f16x8*)(ybuf + (size_t)s0 * DDIM + c*8);
  f16x8 b = *(const f16x8*)(ybuf + (size_t)s1 * DDIM + c*8);
  float4 o0, o1;
  o0.x = (float)a[0] + (float)b[0];
  o0.y = (float)a[1] + (float)b[1];
  o0.z = (float)a[2] + (float)b[2];
  o0.w = (float)a[3] + (float)b[3];
  o1.x = (float)a[4] + (float)b[4];
  o1.y = (float)a[5] + (float)b[5];
  o1.z = (float)a[6] + (float)b[6];
  o1.w = (float)a[7] + (float)b[7];
  float* op = out + (size_t)t * DDIM + c*8;
  *(float4*)op = o0;
  *(float4*)(op + 4) = o1;
}

extern "C" void kernel_launch(void* const* d_in, const int* in_sizes, int n_in,
                              void* d_out, int out_size, void* d_ws, size_t ws_size,
                              hipStream_t stream) {
  const float* x  = (const float*)d_in[0];
  const float* wr = (const float*)d_in[1];
  const float* wg = (const float*)d_in[2];
  const float* wu = (const float*)d_in[3];
  const float* wd = (const float*)d_in[4];
  float* out = (float*)d_out;
  char* ws = (char*)d_ws;
  if (ws_size < WS_NEEDED) return;  // fail loudly (output stays poisoned)

  f16* hbuf  = (f16*)(ws + HBUF_OFF);
  f16* xh    = (f16*)(ws + XH_OFF);
  f16* ybuf  = (f16*)(ws + YBUF_OFF);   // aliases xh (dead by gemm2)
  int* meta  = (int*)(ws + META_OFF);
  float* slot_w = (float*)(ws + SLOTW_OFF);
  float* tok_w  = (float*)(ws + TOKW_OFF);

  hipMemsetAsync(meta + M_COUNT, 0, NEXP * sizeof(int), stream);
  k_router<<<T_TOK/4, 256, 0, stream>>>(x, wr, meta, tok_w);
  k_xcvt<<<(T_TOK*DDIM/8 + 255)/256, 256, 0, stream>>>(x, xh);
  k_scan<<<1, 64, 0, stream>>>(meta, slot_w);
  k_scatter<<<(T_TOK + 255)/256, 256, 0, stream>>>(meta, slot_w, tok_w);
  k_gemm1<<<NB1, 512, 0, stream>>>(xh, wg, wu, hbuf, meta);
  k_gemm2<<<NB2, 512, 0, stream>>>(hbuf, wd, ybuf, meta, slot_w);
  k_combine<<<(T_TOK*DDIM/8 + 255)/256, 256, 0, stream>>>(ybuf, meta, out);
}